// Round 2
// baseline (240.577 us; speedup 1.0000x reference)
//
#include <hip/hip_runtime.h>

#define NLVL 9
#define NPTS 262144

__global__ __launch_bounds__(256) void hashgrid_enc_kernel(
    const float* __restrict__ x,
    const float* __restrict__ table,
    float* __restrict__ out)
{
    const int tid = blockIdx.x * blockDim.x + threadIdx.x;
    if (tid >= NPTS * NLVL) return;
    const int p = tid / NLVL;
    const int l = tid - p * NLVL;

    // load point (9 consecutive threads share one point -> L1 broadcast)
    const float px = x[p * 3 + 0];
    const float py = x[p * 3 + 1];
    const float pz = x[p * 3 + 2];

    const int   s  = 1 << l;
    const float vs = (float)s;

    // norm = (x - DOM_LO)/DOM_LEN = (x+1)*0.5 ; g = norm * 2^l
    const float gx = (px + 1.0f) * 0.5f * vs;
    const float gy = (py + 1.0f) * 0.5f * vs;
    const float gz = (pz + 1.0f) * 0.5f * vs;

    const float bxf = floorf(gx);
    const float byf = floorf(gy);
    const float bzf = floorf(gz);

    const int ix = (int)bxf;
    const int iy = (int)byf;
    const int iz = (int)bzf;

    // trilinear weights: (px - x1)/(x2 - x1) == frac(g) exactly (algebraic identity)
    const float tx = gx - bxf;
    const float ty = gy - byf;
    const float tz = gz - bzf;
    const float ux = 1.0f - tx;
    const float uy = 1.0f - ty;
    const float uz = 1.0f - tz;

    const int s2   = s * s;
    const int f000 = ix + iy * s + iz * s2;

    const float2* __restrict__ tb = (const float2*)table;

    // corner order per reference offsets:
    // 0:(0,0,0) 1:(1,0,0) 2:(0,1,0) 3:(1,1,0) 4:(0,0,1) 5:(1,0,1) 6:(0,1,1) 7:(1,1,1)
    const float2 q0 = tb[f000];
    const float2 q1 = tb[f000 + 1];
    const float2 q2 = tb[f000 + s];
    const float2 q3 = tb[f000 + s + 1];
    const float2 q4 = tb[f000 + s2];
    const float2 q5 = tb[f000 + s2 + 1];
    const float2 q6 = tb[f000 + s2 + s];
    const float2 q7 = tb[f000 + s2 + s + 1];

    // x-interp
    const float fx0a = ux * q0.x + tx * q1.x;
    const float fx0b = ux * q0.y + tx * q1.y;
    const float fx1a = ux * q2.x + tx * q3.x;
    const float fx1b = ux * q2.y + tx * q3.y;
    const float fx2a = ux * q4.x + tx * q5.x;
    const float fx2b = ux * q4.y + tx * q5.y;
    const float fx3a = ux * q6.x + tx * q7.x;
    const float fx3b = ux * q6.y + tx * q7.y;

    // y-interp
    const float fy0a = uy * fx0a + ty * fx1a;
    const float fy0b = uy * fx0b + ty * fx1b;
    const float fy1a = uy * fx2a + ty * fx3a;
    const float fy1b = uy * fx2b + ty * fx3b;

    // z-interp
    float2 r;
    r.x = uz * fy0a + tz * fy1a;
    r.y = uz * fy0b + tz * fy1b;

    // out[p][l*2 .. l*2+1] -> flat index (p*NLVL + l)*2 == tid*2 : coalesced float2 store
    ((float2*)out)[tid] = r;
}

extern "C" void kernel_launch(void* const* d_in, const int* in_sizes, int n_in,
                              void* d_out, int out_size, void* d_ws, size_t ws_size,
                              hipStream_t stream) {
    const float* x     = (const float*)d_in[0];
    const float* table = (const float*)d_in[1];
    float* out = (float*)d_out;

    const int total  = NPTS * NLVL;
    const int block  = 256;
    const int grid   = (total + block - 1) / block;
    hashgrid_enc_kernel<<<grid, block, 0, stream>>>(x, table, out);
}